// Round 21
// baseline (231.966 us; speedup 1.0000x reference)
//
#include <hip/hip_runtime.h>
#include <hip/hip_bf16.h>
#include <math.h>

#define S_LEN 2048
#define B_SZ 4
#define NH 16
#define HD 64
#define C_DIM 1024
#define OUT_DIM 1024

static constexpr size_t BHSD = (size_t)B_SZ * NH * S_LEN * HD; // 8,388,608
#define QSCALE 0.18033688011112042f   /* 0.125 * log2(e): scores in log2 domain */

typedef __attribute__((ext_vector_type(8))) short v8bf;
typedef __attribute__((ext_vector_type(4))) float v4f;
typedef __attribute__((ext_vector_type(4))) unsigned short v4us;

__device__ inline unsigned short f2bf(float x) {
    unsigned u = __float_as_uint(x);
    return (unsigned short)((u + 0x7fffu + ((u >> 16) & 1u)) >> 16);  // RNE
}
__device__ inline unsigned short cvt_bf(float x) {
    __hip_bfloat16 hb = __float2bfloat16(x);
    return reinterpret_cast<unsigned short&>(hb);
}

// ---------------- Kernel 0: fused input conversion (all plain f32 -> bf16) ----------------
__global__ __launch_bounds__(256)
void cvt_all_kernel(const float* __restrict__ x, const float* __restrict__ Wqkv,
                    const float* __restrict__ Wo,
                    unsigned short* __restrict__ xhi, unsigned short* __restrict__ wqh,
                    unsigned short* __restrict__ woh)
{
    constexpr int N_X  = (int)(BHSD / 4);            // 2,097,152
    constexpr int N_WQ = 3 * OUT_DIM * C_DIM / 4;    //   786,432
    const int i = blockIdx.x * 256 + threadIdx.x;
    const float* src;
    unsigned short* dst;
    int k;
    if (i < N_X)             { src = x;    dst = xhi; k = i; }
    else if (i < N_X + N_WQ) { src = Wqkv; dst = wqh; k = i - N_X; }
    else                     { src = Wo;   dst = woh; k = i - N_X - N_WQ; }
    float4 v = reinterpret_cast<const float4*>(src)[k];
    float xx[4] = {v.x, v.y, v.z, v.w};
    v4us h;
#pragma unroll
    for (int j = 0; j < 4; ++j) h[j] = f2bf(xx[j]);
    reinterpret_cast<v4us*>(dst)[k] = h;
}

// ---------------- 1-term bf16 mainloop: 256m x 128n, ring-3, single barrier/K-step ----------------
__device__ __forceinline__ void split1_mainloop_r3(
    const unsigned short* __restrict__ Ahi, const unsigned short* __restrict__ Bhi,
    int an0, int bm0, unsigned short* SA, unsigned short* SB, v4f acc[4][4])
{
    constexpr int K = 1024;
    constexpr int NT = K / 32;
    const int t = threadIdx.x;
    const int lane = t & 63;
    const int w = t >> 6;            // 0..7
    const int wm = w >> 1;           // 0..3
    const int wn = w & 1;            // 0..1
    const int lr = lane & 15, lg = lane >> 4;

    auto STAGE = [&](int kt, int bf) {
        const int k0 = kt * 32;
#pragma unroll
        for (int u = 0; u < 3; ++u) {
            const int c = w * 3 + u;     // 0..23 wave-uniform chunk id
            const unsigned short* src;
            unsigned short* dst;
            if (c < 8) {                 // A: 8 rt-subtiles
                src = Ahi + (size_t)(an0 + c * 16 + lr) * K + k0 + lg * 8;
                dst = SA + bf * 4096 + c * 512;
            } else {                     // B: 16 rt-subtiles
                int rt = c - 8;
                src = Bhi + (size_t)(bm0 + rt * 16 + lr) * K + k0 + lg * 8;
                dst = SB + bf * 8192 + rt * 512;
            }
            __builtin_amdgcn_global_load_lds(
                (const __attribute__((address_space(1))) unsigned int*)src,
                (__attribute__((address_space(3))) unsigned int*)dst, 16, 0, 0);
        }
    };

    STAGE(0, 0);
    STAGE(1, 1);                     // 6 loads/lane outstanding

    for (int kt = 0; kt < NT; ++kt) {
        const int bf = kt % 3;
        if (kt + 1 < NT) { asm volatile("s_waitcnt vmcnt(3)" ::: "memory"); }
        else             { asm volatile("s_waitcnt vmcnt(0)" ::: "memory"); }
        __builtin_amdgcn_s_barrier();
        __builtin_amdgcn_sched_barrier(0);
        if (kt + 2 < NT) STAGE(kt + 2, (kt + 2) % 3);  // readers passed barrier at kt-1

        const unsigned short* sa = SA + bf * 4096;
        const unsigned short* sb = SB + bf * 8192;
        v8bf ah[4], bh[4];
#pragma unroll
        for (int i = 0; i < 4; ++i) {
            ah[i] = *reinterpret_cast<const v8bf*>(sa + (wn * 4 + i) * 512 + lane * 8);
            bh[i] = *reinterpret_cast<const v8bf*>(sb + (wm * 4 + i) * 512 + lane * 8);
        }
        __builtin_amdgcn_s_setprio(1);
#pragma unroll
        for (int q = 0; q < 4; ++q)
#pragma unroll
            for (int nt = 0; nt < 4; ++nt)
                acc[q][nt] = __builtin_amdgcn_mfma_f32_16x16x32_bf16(ah[nt], bh[q], acc[q][nt], 0, 0, 0);
        __builtin_amdgcn_s_setprio(0);
    }
}

// ---------------- Kernel 1: QKV projection (pure bf16, ring-3) ----------------
__global__ __launch_bounds__(512, 4)
void qkv_gemm_mfma(const unsigned short* __restrict__ Whi, const unsigned short* __restrict__ Xhi,
                   const float* __restrict__ bias,
                   unsigned short* __restrict__ qb, unsigned short* __restrict__ kb,
                   unsigned short* __restrict__ vb)
{
    __shared__ __align__(16) unsigned short SA[3 * 4096];    // 24 KB
    __shared__ __align__(16) unsigned short SB[3 * 8192];    // 48 KB
    const v4f zero4 = {0.f, 0.f, 0.f, 0.f};
    v4f acc[4][4];
#pragma unroll
    for (int i = 0; i < 4; ++i)
#pragma unroll
        for (int j = 0; j < 4; ++j) acc[i][j] = zero4;

    const int bm0 = blockIdx.x * 256;
    const int an0 = blockIdx.y * 128;
    split1_mainloop_r3(Whi, Xhi, an0, bm0, SA, SB, acc);

    const int t = threadIdx.x;
    const int lane = t & 63;
    const int w = t >> 6;
    const int wm = w >> 1, wn = w & 1;
    const int lr = lane & 15, lg = lane >> 4;
    const int nbase = an0 + wn * 64;
    const int mbase = bm0 + wm * 64;

#pragma unroll
    for (int nt = 0; nt < 4; ++nt) {
        const int n0 = nbase + nt * 16 + lg * 4;
        const float4 b4 = *reinterpret_cast<const float4*>(bias + n0);
        const float bv[4] = {b4.x, b4.y, b4.z, b4.w};
        const int tsel = n0 >> 10;
        const int np = n0 & 1023;
        const int hh = np >> 6;
        const int dd = np & 63;
#pragma unroll
        for (int mt = 0; mt < 4; ++mt) {
            const int m = mbase + mt * 16 + lr;
            const int s = m >> 2, b = m & 3;
            float vals[4];
#pragma unroll
            for (int r = 0; r < 4; ++r) vals[r] = acc[mt][nt][r] + bv[r];
            if (tsel == 0) {
                v4us h;
#pragma unroll
                for (int r = 0; r < 4; ++r) h[r] = f2bf(vals[r] * QSCALE);
                *reinterpret_cast<v4us*>(qb + ((size_t)(b * NH + hh) * S_LEN + s) * HD + dd) = h;
            } else if (tsel == 1) {
                v4us h;
#pragma unroll
                for (int r = 0; r < 4; ++r) h[r] = f2bf(vals[r]);
                *reinterpret_cast<v4us*>(kb + ((size_t)(b * NH + hh) * S_LEN + s) * HD + dd) = h;
            } else {
#pragma unroll
                for (int r = 0; r < 4; ++r)
                    vb[((size_t)(b * NH + hh) * HD + dd + r) * S_LEN + s] = f2bf(vals[r]);
            }
        }
    }
}

// ---------------- Kernel 2: flash attention — Q-tile 256, 8 waves, 2 blocks/CU exact packing ----------------
// Grid 512 = 64 bh x 8 qt: entire grid co-resident (256 CU x 2 blocks), zero tail.
// Per-wave structure byte-identical to the proven round-18 kernel; STAGE is 2 chunks/wave.
__global__ __launch_bounds__(512, 2)
void attn_kernel(const unsigned short* __restrict__ qb, const unsigned short* __restrict__ kb,
                 const unsigned short* __restrict__ vb, unsigned short* __restrict__ avh)
{
    __shared__ __align__(16) unsigned short SM[2][8192];   // KB@0 (8x512), VT@4096 (8x512)
    __shared__ __align__(16) unsigned short PL[8][2048];   // per-wave P: 32 q rows x 64 kv

    const int t = threadIdx.x;
    const int lane = t & 63;
    const int w = t >> 6;             // 0..7
    const int lr = lane & 15;
    const int lg = lane >> 4;
    const int id = blockIdx.x;
    const int bh = id & 63;           // same-bh blocks share XCD (64 % 8 == 0)
    const int qt = id >> 6;           // 0..7
    const int b = bh >> 4, h = bh & 15;
    const size_t bh_sd = (size_t)bh * (S_LEN * HD);
    const int q0 = qt * 256 + w * 32;
    char* const plw = (char*)&PL[w][0];
    const unsigned swz = (unsigned)((lr & 7) << 4);

    v8bf qh[2][2];
#pragma unroll
    for (int mt = 0; mt < 2; ++mt)
#pragma unroll
        for (int ks = 0; ks < 2; ++ks)
            qh[mt][ks] = *reinterpret_cast<const v8bf*>(
                qb + bh_sd + (size_t)(q0 + mt * 16 + lr) * HD + ks * 32 + lg * 8);

    auto STAGE = [&](int kt, int bf) {
#pragma unroll
        for (int u = 0; u < 2; ++u) {
            int cid = w * 2 + u;          // 0..15
            const unsigned short* src;
            unsigned short* dst;
            if (cid < 8) {                // K tile
                int nt = cid >> 1, kn = cid & 1;
                src = kb + bh_sd + (size_t)(kt * 64 + nt * 16 + lr) * HD + kn * 32 + lg * 8;
                dst = &SM[bf][cid * 512];
            } else {                      // V^T tile
                int n = cid - 8;
                int nt = n >> 1, kn = n & 1;
                src = vb + bh_sd + (size_t)(nt * 16 + lr) * S_LEN + kt * 64 + kn * 32 + lg * 8;
                dst = &SM[bf][4096 + n * 512];
            }
            __builtin_amdgcn_global_load_lds(
                (const __attribute__((address_space(1))) unsigned int*)src,
                (__attribute__((address_space(3))) unsigned int*)dst, 16, 0, 0);
        }
    };

    const v4f zero4 = {0.f, 0.f, 0.f, 0.f};
    v4f O[2][4];
    float m_run[2], l_run[2];
#pragma unroll
    for (int mt = 0; mt < 2; ++mt) { m_run[mt] = -1e30f; l_run[mt] = 0.f; }
#pragma unroll
    for (int mt = 0; mt < 2; ++mt)
#pragma unroll
        for (int nt = 0; nt < 4; ++nt) O[mt][nt] = zero4;

    constexpr int NT = S_LEN / 64;

    STAGE(0, 0);
    asm volatile("s_waitcnt vmcnt(0)" ::: "memory");
    __builtin_amdgcn_s_barrier();
    __builtin_amdgcn_sched_barrier(0);

    for (int kt = 0; kt < NT; ++kt) {
        const int cur = kt & 1;
        if (kt + 1 < NT) STAGE(kt + 1, cur ^ 1);

        const unsigned short* KB = &SM[cur][0];
        const unsigned short* VT = &SM[cur][4096];

        // ---- swapped QK^T: sc[mt][nt][r] = S[kv=nt*16+lg*4+r][q=mt*16+lr] ----
        v4f sc[2][4];
#pragma unroll
        for (int mt = 0; mt < 2; ++mt)
#pragma unroll
            for (int nt = 0; nt < 4; ++nt) sc[mt][nt] = zero4;
        __builtin_amdgcn_s_setprio(1);
#pragma unroll
        for (int ks = 0; ks < 2; ++ks)
#pragma unroll
            for (int nt = 0; nt < 4; ++nt) {
                v8bf kh = *reinterpret_cast<const v8bf*>(KB + (nt * 2 + ks) * 512 + lane * 8);
#pragma unroll
                for (int mt = 0; mt < 2; ++mt)
                    sc[mt][nt] = __builtin_amdgcn_mfma_f32_16x16x32_bf16(kh, qh[mt][ks], sc[mt][nt], 0, 0, 0);
            }
        __builtin_amdgcn_s_setprio(0);

        // ---- softmax (lane-local rows; tree max) ----
        float rm[2];
        bool need = false;
#pragma unroll
        for (int mt = 0; mt < 2; ++mt) {
            float m0 = fmaxf(fmaxf(sc[mt][0][0], sc[mt][0][1]), fmaxf(sc[mt][0][2], sc[mt][0][3]));
            float m1 = fmaxf(fmaxf(sc[mt][1][0], sc[mt][1][1]), fmaxf(sc[mt][1][2], sc[mt][1][3]));
            float m2 = fmaxf(fmaxf(sc[mt][2][0], sc[mt][2][1]), fmaxf(sc[mt][2][2], sc[mt][2][3]));
            float m3 = fmaxf(fmaxf(sc[mt][3][0], sc[mt][3][1]), fmaxf(sc[mt][3][2], sc[mt][3][3]));
            float lm = fmaxf(fmaxf(m0, m1), fmaxf(m2, m3));
            lm = fmaxf(lm, __shfl_xor(lm, 16));
            lm = fmaxf(lm, __shfl_xor(lm, 32));
            rm[mt] = lm;
            need = need || (lm > m_run[mt] + 8.0f);
        }
        if (__any(need)) {           // defer-max (T13)
#pragma unroll
            for (int mt = 0; mt < 2; ++mt) {
                float nm = fmaxf(m_run[mt], rm[mt]);
                float alpha = __builtin_amdgcn_exp2f(m_run[mt] - nm);
                m_run[mt] = nm;
                l_run[mt] *= alpha;
                float af[4];
#pragma unroll
                for (int r = 0; r < 4; ++r) af[r] = __shfl(alpha, lg * 4 + r);
#pragma unroll
                for (int nt = 0; nt < 4; ++nt)
#pragma unroll
                    for (int r = 0; r < 4; ++r) O[mt][nt][r] *= af[r];
            }
        }
#pragma unroll
        for (int mt = 0; mt < 2; ++mt) {
            float rs = 0.f;
#pragma unroll
            for (int nt = 0; nt < 4; ++nt) {
                v4us pp;
#pragma unroll
                for (int r = 0; r < 4; ++r) {
                    float p = __builtin_amdgcn_exp2f(sc[mt][nt][r] - m_run[mt]);
                    rs += p;
                    pp[r] = cvt_bf(p);
                }
                unsigned wb = (unsigned)((mt * 16 + lr) * 128 + (nt * 16 + lg * 4) * 2) ^ swz;
                *reinterpret_cast<v4us*>(plw + wb) = pp;
            }
            rs += __shfl_xor(rs, 16);
            rs += __shfl_xor(rs, 32);
            l_run[mt] += rs;
        }
        asm volatile("s_waitcnt lgkmcnt(0)" ::: "memory");
        __builtin_amdgcn_sched_barrier(0);

        // ---- PV ----
        __builtin_amdgcn_s_setprio(1);
#pragma unroll
        for (int ks = 0; ks < 2; ++ks) {
            v8bf pa[2];
#pragma unroll
            for (int mt = 0; mt < 2; ++mt) {
                unsigned rb = (unsigned)((mt * 16 + lr) * 128 + (ks * 32 + lg * 8) * 2) ^ swz;
                pa[mt] = *reinterpret_cast<const v8bf*>(plw + rb);
            }
#pragma unroll
            for (int nt = 0; nt < 4; ++nt) {
                v8bf vf = *reinterpret_cast<const v8bf*>(VT + (nt * 2 + ks) * 512 + lane * 8);
#pragma unroll
                for (int mt = 0; mt < 2; ++mt)
                    O[mt][nt] = __builtin_amdgcn_mfma_f32_16x16x32_bf16(pa[mt], vf, O[mt][nt], 0, 0, 0);
            }
        }
        __builtin_amdgcn_s_setprio(0);

        asm volatile("s_waitcnt vmcnt(0)" ::: "memory");
        __builtin_amdgcn_s_barrier();
        __builtin_amdgcn_sched_barrier(0);
    }

    // epilogue
#pragma unroll
    for (int mt = 0; mt < 2; ++mt) {
        float linv = 1.f / l_run[mt];
#pragma unroll
        for (int r = 0; r < 4; ++r) {
            float inv = __shfl(linv, lg * 4 + r);
            int s = q0 + mt * 16 + lg * 4 + r;
            size_t base = (size_t)(b * S_LEN + s) * OUT_DIM + h * HD;
#pragma unroll
            for (int nt = 0; nt < 4; ++nt)
                avh[base + nt * 16 + lr] = cvt_bf(O[mt][nt][r] * inv);
        }
    }
}

// ---------------- Kernel 3: output projection (pure bf16, ring-3) ----------------
__global__ __launch_bounds__(512, 4)
void out_gemm_mfma(const unsigned short* __restrict__ Whi, const unsigned short* __restrict__ Bhi,
                   const float* __restrict__ bias, float* __restrict__ out)
{
    __shared__ __align__(16) unsigned short SA[3 * 4096];    // 24 KB
    __shared__ __align__(16) unsigned short SB[3 * 8192];    // 48 KB
    const v4f zero4 = {0.f, 0.f, 0.f, 0.f};
    v4f acc[4][4];
#pragma unroll
    for (int i = 0; i < 4; ++i)
#pragma unroll
        for (int j = 0; j < 4; ++j) acc[i][j] = zero4;

    const int bm0 = blockIdx.x * 256;
    const int an0 = blockIdx.y * 128;
    split1_mainloop_r3(Whi, Bhi, an0, bm0, SA, SB, acc);

    const int t = threadIdx.x;
    const int lane = t & 63;
    const int w = t >> 6;
    const int wm = w >> 1, wn = w & 1;
    const int lr = lane & 15, lg = lane >> 4;
    const int nbase = an0 + wn * 64;
    const int mbase = bm0 + wm * 64;

#pragma unroll
    for (int nt = 0; nt < 4; ++nt) {
        const int n0 = nbase + nt * 16 + lg * 4;
        const float4 b4 = *reinterpret_cast<const float4*>(bias + n0);
#pragma unroll
        for (int mt = 0; mt < 4; ++mt) {
            const int m = mbase + mt * 16 + lr;
            float4 o = make_float4(acc[mt][nt][0] + b4.x, acc[mt][nt][1] + b4.y,
                                   acc[mt][nt][2] + b4.z, acc[mt][nt][3] + b4.w);
            *reinterpret_cast<float4*>(out + (size_t)m * OUT_DIM + n0) = o;
        }
    }
}

extern "C" void kernel_launch(void* const* d_in, const int* in_sizes, int n_in,
                              void* d_out, int out_size, void* d_ws, size_t ws_size,
                              hipStream_t stream)
{
    const float* x    = (const float*)d_in[0];
    const float* Wqkv = (const float*)d_in[1];
    const float* bqkv = (const float*)d_in[2];
    const float* Wo   = (const float*)d_in[3];
    const float* bo   = (const float*)d_in[4];
    float* out = (float*)d_out;

    unsigned short* p = (unsigned short*)d_ws;
    unsigned short* xhi = p;            p += BHSD;                 // 8192x1024 bf16
    unsigned short* wqh = p;            p += 3 * OUT_DIM * C_DIM;
    unsigned short* woh = p;            p += OUT_DIM * OUT_DIM;
    unsigned short* qb = p;             p += BHSD;
    unsigned short* kb = p;             p += BHSD;
    unsigned short* vb = p;             p += BHSD;
    unsigned short* avh = xhi;          // x dead after qkv_gemm -> reuse

    cvt_all_kernel<<<dim3(12288), 256, 0, stream>>>(x, Wqkv, Wo, xhi, wqh, woh);

    qkv_gemm_mfma<<<dim3(32, 24), 512, 0, stream>>>(wqh, xhi, bqkv, qb, kb, vb);
    attn_kernel<<<dim3(512), 512, 0, stream>>>(qb, kb, vb, avh);
    out_gemm_mfma<<<dim3(32, 8), 512, 0, stream>>>(woh, avh, bo, out);
}

// Round 22
// 229.319 us; speedup vs baseline: 1.0115x; 1.0115x over previous
//
#include <hip/hip_runtime.h>
#include <hip/hip_bf16.h>
#include <math.h>

#define S_LEN 2048
#define B_SZ 4
#define NH 16
#define HD 64
#define C_DIM 1024
#define OUT_DIM 1024

static constexpr size_t BHSD = (size_t)B_SZ * NH * S_LEN * HD; // 8,388,608
#define QSCALE 0.18033688011112042f   /* 0.125 * log2(e): scores in log2 domain */

typedef __attribute__((ext_vector_type(8))) short v8bf;
typedef __attribute__((ext_vector_type(4))) float v4f;
typedef __attribute__((ext_vector_type(4))) unsigned short v4us;

__device__ inline unsigned short f2bf(float x) {
    unsigned u = __float_as_uint(x);
    return (unsigned short)((u + 0x7fffu + ((u >> 16) & 1u)) >> 16);  // RNE
}
__device__ inline unsigned short cvt_bf(float x) {
    __hip_bfloat16 hb = __float2bfloat16(x);
    return reinterpret_cast<unsigned short&>(hb);
}

// ---------------- Kernel 0: fused input conversion (all plain f32 -> bf16) ----------------
__global__ __launch_bounds__(256)
void cvt_all_kernel(const float* __restrict__ x, const float* __restrict__ Wqkv,
                    const float* __restrict__ Wo,
                    unsigned short* __restrict__ xhi, unsigned short* __restrict__ wqh,
                    unsigned short* __restrict__ woh)
{
    constexpr int N_X  = (int)(BHSD / 4);            // 2,097,152
    constexpr int N_WQ = 3 * OUT_DIM * C_DIM / 4;    //   786,432
    const int i = blockIdx.x * 256 + threadIdx.x;
    const float* src;
    unsigned short* dst;
    int k;
    if (i < N_X)             { src = x;    dst = xhi; k = i; }
    else if (i < N_X + N_WQ) { src = Wqkv; dst = wqh; k = i - N_X; }
    else                     { src = Wo;   dst = woh; k = i - N_X - N_WQ; }
    float4 v = reinterpret_cast<const float4*>(src)[k];
    float xx[4] = {v.x, v.y, v.z, v.w};
    v4us h;
#pragma unroll
    for (int j = 0; j < 4; ++j) h[j] = f2bf(xx[j]);
    reinterpret_cast<v4us*>(dst)[k] = h;
}

// ---------------- 1-term bf16 mainloop: 256m x 128n, ring-3, single barrier/K-step ----------------
__device__ __forceinline__ void split1_mainloop_r3(
    const unsigned short* __restrict__ Ahi, const unsigned short* __restrict__ Bhi,
    int an0, int bm0, unsigned short* SA, unsigned short* SB, v4f acc[4][4])
{
    constexpr int K = 1024;
    constexpr int NT = K / 32;
    const int t = threadIdx.x;
    const int lane = t & 63;
    const int w = t >> 6;            // 0..7
    const int wm = w >> 1;           // 0..3
    const int wn = w & 1;            // 0..1
    const int lr = lane & 15, lg = lane >> 4;

    auto STAGE = [&](int kt, int bf) {
        const int k0 = kt * 32;
#pragma unroll
        for (int u = 0; u < 3; ++u) {
            const int c = w * 3 + u;     // 0..23 wave-uniform chunk id
            const unsigned short* src;
            unsigned short* dst;
            if (c < 8) {                 // A: 8 rt-subtiles
                src = Ahi + (size_t)(an0 + c * 16 + lr) * K + k0 + lg * 8;
                dst = SA + bf * 4096 + c * 512;
            } else {                     // B: 16 rt-subtiles
                int rt = c - 8;
                src = Bhi + (size_t)(bm0 + rt * 16 + lr) * K + k0 + lg * 8;
                dst = SB + bf * 8192 + rt * 512;
            }
            __builtin_amdgcn_global_load_lds(
                (const __attribute__((address_space(1))) unsigned int*)src,
                (__attribute__((address_space(3))) unsigned int*)dst, 16, 0, 0);
        }
    };

    STAGE(0, 0);
    STAGE(1, 1);                     // 6 loads/lane outstanding

    for (int kt = 0; kt < NT; ++kt) {
        const int bf = kt % 3;
        if (kt + 1 < NT) { asm volatile("s_waitcnt vmcnt(3)" ::: "memory"); }
        else             { asm volatile("s_waitcnt vmcnt(0)" ::: "memory"); }
        __builtin_amdgcn_s_barrier();
        __builtin_amdgcn_sched_barrier(0);
        if (kt + 2 < NT) STAGE(kt + 2, (kt + 2) % 3);  // readers passed barrier at kt-1

        const unsigned short* sa = SA + bf * 4096;
        const unsigned short* sb = SB + bf * 8192;
        v8bf ah[4], bh[4];
#pragma unroll
        for (int i = 0; i < 4; ++i) {
            ah[i] = *reinterpret_cast<const v8bf*>(sa + (wn * 4 + i) * 512 + lane * 8);
            bh[i] = *reinterpret_cast<const v8bf*>(sb + (wm * 4 + i) * 512 + lane * 8);
        }
        __builtin_amdgcn_s_setprio(1);
#pragma unroll
        for (int q = 0; q < 4; ++q)
#pragma unroll
            for (int nt = 0; nt < 4; ++nt)
                acc[q][nt] = __builtin_amdgcn_mfma_f32_16x16x32_bf16(ah[nt], bh[q], acc[q][nt], 0, 0, 0);
        __builtin_amdgcn_s_setprio(0);
    }
}

// ---------------- Kernel 1: QKV projection (pure bf16, ring-3) ----------------
__global__ __launch_bounds__(512, 4)
void qkv_gemm_mfma(const unsigned short* __restrict__ Whi, const unsigned short* __restrict__ Xhi,
                   const float* __restrict__ bias,
                   unsigned short* __restrict__ qb, unsigned short* __restrict__ kb,
                   unsigned short* __restrict__ vb)
{
    __shared__ __align__(16) unsigned short SA[3 * 4096];    // 24 KB
    __shared__ __align__(16) unsigned short SB[3 * 8192];    // 48 KB
    const v4f zero4 = {0.f, 0.f, 0.f, 0.f};
    v4f acc[4][4];
#pragma unroll
    for (int i = 0; i < 4; ++i)
#pragma unroll
        for (int j = 0; j < 4; ++j) acc[i][j] = zero4;

    const int bm0 = blockIdx.x * 256;
    const int an0 = blockIdx.y * 128;
    split1_mainloop_r3(Whi, Xhi, an0, bm0, SA, SB, acc);

    const int t = threadIdx.x;
    const int lane = t & 63;
    const int w = t >> 6;
    const int wm = w >> 1, wn = w & 1;
    const int lr = lane & 15, lg = lane >> 4;
    const int nbase = an0 + wn * 64;
    const int mbase = bm0 + wm * 64;

#pragma unroll
    for (int nt = 0; nt < 4; ++nt) {
        const int n0 = nbase + nt * 16 + lg * 4;
        const float4 b4 = *reinterpret_cast<const float4*>(bias + n0);
        const float bv[4] = {b4.x, b4.y, b4.z, b4.w};
        const int tsel = n0 >> 10;
        const int np = n0 & 1023;
        const int hh = np >> 6;
        const int dd = np & 63;
#pragma unroll
        for (int mt = 0; mt < 4; ++mt) {
            const int m = mbase + mt * 16 + lr;
            const int s = m >> 2, b = m & 3;
            float vals[4];
#pragma unroll
            for (int r = 0; r < 4; ++r) vals[r] = acc[mt][nt][r] + bv[r];
            if (tsel == 0) {
                v4us h;
#pragma unroll
                for (int r = 0; r < 4; ++r) h[r] = f2bf(vals[r] * QSCALE);
                *reinterpret_cast<v4us*>(qb + ((size_t)(b * NH + hh) * S_LEN + s) * HD + dd) = h;
            } else if (tsel == 1) {
                v4us h;
#pragma unroll
                for (int r = 0; r < 4; ++r) h[r] = f2bf(vals[r]);
                *reinterpret_cast<v4us*>(kb + ((size_t)(b * NH + hh) * S_LEN + s) * HD + dd) = h;
            } else {
#pragma unroll
                for (int r = 0; r < 4; ++r)
                    vb[((size_t)(b * NH + hh) * HD + dd + r) * S_LEN + s] = f2bf(vals[r]);
            }
        }
    }
}

// ---------------- Kernel 2: flash attention — bf16 QK^T, swapped operands (session-best) ----------------
__global__ __launch_bounds__(256, 3)
void attn_kernel(const unsigned short* __restrict__ qb, const unsigned short* __restrict__ kb,
                 const unsigned short* __restrict__ vb, unsigned short* __restrict__ avh)
{
    __shared__ __align__(16) unsigned short SM[2][8192];   // KB@0 (8x512), VT@4096 (8x512)
    __shared__ __align__(16) unsigned short PL[4][32 * 64];  // per-wave P, XOR-swizzled

    const int t = threadIdx.x;
    const int lane = t & 63;
    const int w = t >> 6;
    const int lr = lane & 15;
    const int lg = lane >> 4;
    const int id = blockIdx.x;
    const int bh = id & 63;           // same-bh blocks share XCD (64 % 8 == 0)
    const int qt = id >> 6;
    const int b = bh >> 4, h = bh & 15;
    const size_t bh_sd = (size_t)bh * (S_LEN * HD);
    const int q0 = qt * 128 + w * 32;
    char* const plw = (char*)&PL[w][0];
    const unsigned swz = (unsigned)((lr & 7) << 4);

    v8bf qh[2][2];
#pragma unroll
    for (int mt = 0; mt < 2; ++mt)
#pragma unroll
        for (int ks = 0; ks < 2; ++ks)
            qh[mt][ks] = *reinterpret_cast<const v8bf*>(
                qb + bh_sd + (size_t)(q0 + mt * 16 + lr) * HD + ks * 32 + lg * 8);

    auto STAGE = [&](int kt, int bf) {
#pragma unroll
        for (int u = 0; u < 4; ++u) {
            int cid = w * 4 + u;          // 0..15
            const unsigned short* src;
            unsigned short* dst;
            if (cid < 8) {                // K tile
                int nt = cid >> 1, kn = cid & 1;
                src = kb + bh_sd + (size_t)(kt * 64 + nt * 16 + lr) * HD + kn * 32 + lg * 8;
                dst = &SM[bf][cid * 512];
            } else {                      // V^T tile
                int n = cid - 8;
                int nt = n >> 1, kn = n & 1;
                src = vb + bh_sd + (size_t)(nt * 16 + lr) * S_LEN + kt * 64 + kn * 32 + lg * 8;
                dst = &SM[bf][4096 + n * 512];
            }
            __builtin_amdgcn_global_load_lds(
                (const __attribute__((address_space(1))) unsigned int*)src,
                (__attribute__((address_space(3))) unsigned int*)dst, 16, 0, 0);
        }
    };

    const v4f zero4 = {0.f, 0.f, 0.f, 0.f};
    v4f O[2][4];
    float m_run[2], l_run[2];
#pragma unroll
    for (int mt = 0; mt < 2; ++mt) { m_run[mt] = -1e30f; l_run[mt] = 0.f; }
#pragma unroll
    for (int mt = 0; mt < 2; ++mt)
#pragma unroll
        for (int nt = 0; nt < 4; ++nt) O[mt][nt] = zero4;

    constexpr int NT = S_LEN / 64;

    STAGE(0, 0);
    asm volatile("s_waitcnt vmcnt(0)" ::: "memory");
    __builtin_amdgcn_s_barrier();
    __builtin_amdgcn_sched_barrier(0);

    for (int kt = 0; kt < NT; ++kt) {
        const int cur = kt & 1;
        if (kt + 1 < NT) STAGE(kt + 1, cur ^ 1);

        const unsigned short* KB = &SM[cur][0];
        const unsigned short* VT = &SM[cur][4096];

        // ---- swapped QK^T: sc[mt][nt][r] = S[kv=nt*16+lg*4+r][q=mt*16+lr] ----
        v4f sc[2][4];
#pragma unroll
        for (int mt = 0; mt < 2; ++mt)
#pragma unroll
            for (int nt = 0; nt < 4; ++nt) sc[mt][nt] = zero4;
        __builtin_amdgcn_s_setprio(1);
#pragma unroll
        for (int ks = 0; ks < 2; ++ks)
#pragma unroll
            for (int nt = 0; nt < 4; ++nt) {
                v8bf kh = *reinterpret_cast<const v8bf*>(KB + (nt * 2 + ks) * 512 + lane * 8);
#pragma unroll
                for (int mt = 0; mt < 2; ++mt)
                    sc[mt][nt] = __builtin_amdgcn_mfma_f32_16x16x32_bf16(kh, qh[mt][ks], sc[mt][nt], 0, 0, 0);
            }
        __builtin_amdgcn_s_setprio(0);

        // ---- softmax (lane-local rows; tree max) ----
        float rm[2];
        bool need = false;
#pragma unroll
        for (int mt = 0; mt < 2; ++mt) {
            float m0 = fmaxf(fmaxf(sc[mt][0][0], sc[mt][0][1]), fmaxf(sc[mt][0][2], sc[mt][0][3]));
            float m1 = fmaxf(fmaxf(sc[mt][1][0], sc[mt][1][1]), fmaxf(sc[mt][1][2], sc[mt][1][3]));
            float m2 = fmaxf(fmaxf(sc[mt][2][0], sc[mt][2][1]), fmaxf(sc[mt][2][2], sc[mt][2][3]));
            float m3 = fmaxf(fmaxf(sc[mt][3][0], sc[mt][3][1]), fmaxf(sc[mt][3][2], sc[mt][3][3]));
            float lm = fmaxf(fmaxf(m0, m1), fmaxf(m2, m3));
            lm = fmaxf(lm, __shfl_xor(lm, 16));
            lm = fmaxf(lm, __shfl_xor(lm, 32));
            rm[mt] = lm;
            need = need || (lm > m_run[mt] + 8.0f);
        }
        if (__any(need)) {           // defer-max (T13)
#pragma unroll
            for (int mt = 0; mt < 2; ++mt) {
                float nm = fmaxf(m_run[mt], rm[mt]);
                float alpha = __builtin_amdgcn_exp2f(m_run[mt] - nm);
                m_run[mt] = nm;
                l_run[mt] *= alpha;
                float af[4];
#pragma unroll
                for (int r = 0; r < 4; ++r) af[r] = __shfl(alpha, lg * 4 + r);
#pragma unroll
                for (int nt = 0; nt < 4; ++nt)
#pragma unroll
                    for (int r = 0; r < 4; ++r) O[mt][nt][r] *= af[r];
            }
        }
#pragma unroll
        for (int mt = 0; mt < 2; ++mt) {
            float rs = 0.f;
#pragma unroll
            for (int nt = 0; nt < 4; ++nt) {
                v4us pp;
#pragma unroll
                for (int r = 0; r < 4; ++r) {
                    float p = __builtin_amdgcn_exp2f(sc[mt][nt][r] - m_run[mt]);
                    rs += p;
                    pp[r] = cvt_bf(p);
                }
                unsigned wb = (unsigned)((mt * 16 + lr) * 128 + (nt * 16 + lg * 4) * 2) ^ swz;
                *reinterpret_cast<v4us*>(plw + wb) = pp;
            }
            rs += __shfl_xor(rs, 16);
            rs += __shfl_xor(rs, 32);
            l_run[mt] += rs;
        }
        asm volatile("s_waitcnt lgkmcnt(0)" ::: "memory");
        __builtin_amdgcn_sched_barrier(0);

        // ---- PV ----
        __builtin_amdgcn_s_setprio(1);
#pragma unroll
        for (int ks = 0; ks < 2; ++ks) {
            v8bf pa[2];
#pragma unroll
            for (int mt = 0; mt < 2; ++mt) {
                unsigned rb = (unsigned)((mt * 16 + lr) * 128 + (ks * 32 + lg * 8) * 2) ^ swz;
                pa[mt] = *reinterpret_cast<const v8bf*>(plw + rb);
            }
#pragma unroll
            for (int nt = 0; nt < 4; ++nt) {
                v8bf vf = *reinterpret_cast<const v8bf*>(VT + (nt * 2 + ks) * 512 + lane * 8);
#pragma unroll
                for (int mt = 0; mt < 2; ++mt)
                    O[mt][nt] = __builtin_amdgcn_mfma_f32_16x16x32_bf16(pa[mt], vf, O[mt][nt], 0, 0, 0);
            }
        }
        __builtin_amdgcn_s_setprio(0);

        asm volatile("s_waitcnt vmcnt(0)" ::: "memory");
        __builtin_amdgcn_s_barrier();
        __builtin_amdgcn_sched_barrier(0);
    }

    // epilogue
#pragma unroll
    for (int mt = 0; mt < 2; ++mt) {
        float linv = 1.f / l_run[mt];
#pragma unroll
        for (int r = 0; r < 4; ++r) {
            float inv = __shfl(linv, lg * 4 + r);
            int s = q0 + mt * 16 + lg * 4 + r;
            size_t base = (size_t)(b * S_LEN + s) * OUT_DIM + h * HD;
#pragma unroll
            for (int nt = 0; nt < 4; ++nt)
                avh[base + nt * 16 + lr] = cvt_bf(O[mt][nt][r] * inv);
        }
    }
}

// ---------------- Kernel 3: output projection (pure bf16, ring-3) ----------------
__global__ __launch_bounds__(512, 4)
void out_gemm_mfma(const unsigned short* __restrict__ Whi, const unsigned short* __restrict__ Bhi,
                   const float* __restrict__ bias, float* __restrict__ out)
{
    __shared__ __align__(16) unsigned short SA[3 * 4096];    // 24 KB
    __shared__ __align__(16) unsigned short SB[3 * 8192];    // 48 KB
    const v4f zero4 = {0.f, 0.f, 0.f, 0.f};
    v4f acc[4][4];
#pragma unroll
    for (int i = 0; i < 4; ++i)
#pragma unroll
        for (int j = 0; j < 4; ++j) acc[i][j] = zero4;

    const int bm0 = blockIdx.x * 256;
    const int an0 = blockIdx.y * 128;
    split1_mainloop_r3(Whi, Bhi, an0, bm0, SA, SB, acc);

    const int t = threadIdx.x;
    const int lane = t & 63;
    const int w = t >> 6;
    const int wm = w >> 1, wn = w & 1;
    const int lr = lane & 15, lg = lane >> 4;
    const int nbase = an0 + wn * 64;
    const int mbase = bm0 + wm * 64;

#pragma unroll
    for (int nt = 0; nt < 4; ++nt) {
        const int n0 = nbase + nt * 16 + lg * 4;
        const float4 b4 = *reinterpret_cast<const float4*>(bias + n0);
#pragma unroll
        for (int mt = 0; mt < 4; ++mt) {
            const int m = mbase + mt * 16 + lr;
            float4 o = make_float4(acc[mt][nt][0] + b4.x, acc[mt][nt][1] + b4.y,
                                   acc[mt][nt][2] + b4.z, acc[mt][nt][3] + b4.w);
            *reinterpret_cast<float4*>(out + (size_t)m * OUT_DIM + n0) = o;
        }
    }
}

extern "C" void kernel_launch(void* const* d_in, const int* in_sizes, int n_in,
                              void* d_out, int out_size, void* d_ws, size_t ws_size,
                              hipStream_t stream)
{
    const float* x    = (const float*)d_in[0];
    const float* Wqkv = (const float*)d_in[1];
    const float* bqkv = (const float*)d_in[2];
    const float* Wo   = (const float*)d_in[3];
    const float* bo   = (const float*)d_in[4];
    float* out = (float*)d_out;

    unsigned short* p = (unsigned short*)d_ws;
    unsigned short* xhi = p;            p += BHSD;                 // 8192x1024 bf16
    unsigned short* wqh = p;            p += 3 * OUT_DIM * C_DIM;
    unsigned short* woh = p;            p += OUT_DIM * OUT_DIM;
    unsigned short* qb = p;             p += BHSD;
    unsigned short* kb = p;             p += BHSD;
    unsigned short* vb = p;             p += BHSD;
    unsigned short* avh = xhi;          // x dead after qkv_gemm -> reuse

    cvt_all_kernel<<<dim3(12288), 256, 0, stream>>>(x, Wqkv, Wo, xhi, wqh, woh);

    qkv_gemm_mfma<<<dim3(32, 24), 512, 0, stream>>>(wqh, xhi, bqkv, qb, kb, vb);
    attn_kernel<<<dim3(1024), 256, 0, stream>>>(qb, kb, vb, avh);
    out_gemm_mfma<<<dim3(32, 8), 512, 0, stream>>>(woh, avh, bo, out);
}